// Round 1
// baseline (757.213 us; speedup 1.0000x reference)
//
#include <hip/hip_runtime.h>
#include <stdint.h>

typedef unsigned int uint32;
typedef unsigned short u16;
typedef short short8 __attribute__((ext_vector_type(8)));
typedef float floatx4 __attribute__((ext_vector_type(4)));

// ---------------- workspace layout (bytes) ----------------
#define OFF_S      0u           // s[16][512] f32        : 32768
#define OFF_DS     32768u       // dscale[16][512] f32   : 32768
#define OFF_WSUM   65536u       // wsum[512][512] f32    : 1 MB
#define OFF_WPACK  1114112u     // wpack[9][512][512] bf16: 4.5 MB
#define OFF_XST    5832704u     // xst[16][32][32][512] bf16: 16 MB
#define OFF_T      22609920u    // t[16][512][4225] bf16 : 69.2 MB
// total ~91.8 MB

__device__ __forceinline__ u16 f2bf(float x){
    uint32 u = __float_as_uint(x);
    uint32 r = (u + 0x7FFFu + ((u>>16)&1u)) >> 16;
    return (u16)r;
}
__device__ __forceinline__ float bf2f(u16 h){
    return __uint_as_float(((uint32)h)<<16);
}

// ---- s[b][ic] = style[b]·mod_weight[ic] * mod_scale + mod_bias[ic] ----
__global__ __launch_bounds__(256) void k_style(const float* __restrict__ style,
                                               const float* __restrict__ mw,
                                               const float* __restrict__ mb,
                                               float* __restrict__ s){
    int gid = blockIdx.x*4 + (threadIdx.x>>6);
    int lane = threadIdx.x & 63;
    int b = gid>>9, ic = gid & 511;
    const float* sp = style + b*512;
    const float* wp = mw + (size_t)ic*512;
    float acc = 0.f;
    for (int d=lane; d<512; d+=64) acc += sp[d]*wp[d];
    for (int off=32; off; off>>=1) acc += __shfl_down(acc, off, 64);
    if (lane==0) s[b*512+ic] = acc*0.044194173824159216f + mb[ic]; // 1/sqrt(512)
}

// ---- wsum[oc][ic] = sum_k w^2 ----
__global__ __launch_bounds__(256) void k_wsum(const float* __restrict__ w,
                                              float* __restrict__ wsum){
    int idx = blockIdx.x*256 + threadIdx.x; // 262144
    const float* p = w + (size_t)idx*9;
    float a=0.f;
    #pragma unroll
    for (int i=0;i<9;++i){ float v=p[i]; a += v*v; }
    wsum[idx] = a;
}

// ---- dscale[b][oc] = conv_scale * rsqrt(conv_scale^2 * sum_ic s^2*wsum + eps) ----
__global__ __launch_bounds__(256) void k_dscale(const float* __restrict__ s,
                                                const float* __restrict__ wsum,
                                                float* __restrict__ ds){
    int gid = blockIdx.x*4 + (threadIdx.x>>6);
    int lane = threadIdx.x & 63;
    int b = gid>>9, oc = gid & 511;
    const float* sp = s + b*512;
    const float* wp = wsum + (size_t)oc*512;
    float acc=0.f;
    for (int d=lane; d<512; d+=64){ float sv = sp[d]; acc += sv*sv*wp[d]; }
    for (int off=32; off; off>>=1) acc += __shfl_down(acc, off, 64);
    if (lane==0){
        const float cs = 0.014731391274719738f; // 1/sqrt(512*9)
        ds[b*512+oc] = cs * rsqrtf(cs*cs*acc + 1e-8f);
    }
}

// ---- wpack[a*3+b][oc][ic] = bf16(weight[0][oc][ic][a][b]) (unflipped) ----
__global__ __launch_bounds__(256) void k_wpack(const float* __restrict__ w,
                                               u16* __restrict__ wp){
    int idx = blockIdx.x*256 + threadIdx.x; // oc*512+ic
    const float* p = w + (size_t)idx*9;
    #pragma unroll
    for (int t=0;t<9;++t) wp[(size_t)t*262144 + idx] = f2bf(p[t]);
}

// ---- xst[b][i][j][ic] = bf16(input[b][ic][i][j] * s[b][ic]) ----
__global__ __launch_bounds__(256) void k_xst(const float* __restrict__ in,
                                             const float* __restrict__ s,
                                             u16* __restrict__ xst){
    int bx = blockIdx.x;
    int b = bx>>5, i = bx&31;
    int j = threadIdx.x & 31, icl = threadIdx.x>>5;
    for (int ic=icl; ic<512; ic+=8){
        float v = in[(((size_t)(b*512+ic))*32 + i)*32 + j] * s[b*512+ic];
        xst[((size_t)(b*1024 + i*32 + j))*512 + ic] = f2bf(v);
    }
}

// ---- stage 1: parity-decomposed transposed conv, bf16 MFMA ----
// t[y][x] = sum_{a: y-a even, i=(y-a)/2 in [0,32)} sum_{bb sim.} w[oc,ic,a,bb]*xs[i,j]
// class c=(py,px): sub-image t_c[Y'][X'], taps (di,dj) in {0..na-1}x{0..nb-1},
// a=py+2*di, input row i = Y'-di.  Block: 64 oc x 64 px (8x8), 4 waves 2x2.
__global__ __launch_bounds__(256) void k_conv(const u16* __restrict__ wpack,
                                              const u16* __restrict__ xst,
                                              u16* __restrict__ tout){
    int tt = blockIdx.x;        // 0..80 pixel tile across classes
    int m0 = blockIdx.y * 64;   // oc tile
    int b  = blockIdx.z;

    int c, loc, TC;
    if (tt < 25)      { c=0; loc=tt;    TC=5; }
    else if (tt < 45) { c=1; loc=tt-25; TC=4; }
    else if (tt < 65) { c=2; loc=tt-45; TC=5; }
    else              { c=3; loc=tt-65; TC=4; }
    int py = c>>1, px = c&1;
    int Hc = py?32:33, Wc = px?32:33;
    int tr = loc/TC, tc = loc - tr*TC;
    int Y0 = tr*8, X0 = tc*8;
    int offc = (c==0)?0:(c==1)?1089:(c==2)?2145:3201;

    int na = py?1:2, nb = px?1:2;
    int ntap = na*nb;
    int dis[4], djs[4], pls[4];
    {
        int q_=0;
        for (int u=0; u<na; ++u)
            for (int v=0; v<nb; ++v){
                dis[q_]=u; djs[q_]=v; pls[q_]=(py+2*u)*3 + (px+2*v); ++q_;
            }
    }

    __shared__ __align__(16) u16 Asm[4*64*32];  // [tap][oc64][ic32]
    __shared__ __align__(16) u16 Xsm[81*32];    // [9x9 halo px][ic32]

    int tid = threadIdx.x;
    int lane = tid & 63;
    int wid  = tid >> 6;
    int wy = wid>>1, wx = wid&1;
    int np = lane & 15, qq = lane >> 4;

    int aoff0 = (wy*32 +  0 + np)*32 + qq*8;
    int aoff1 = (wy*32 + 16 + np)*32 + qq*8;
    int xoff[4][2];
    for (int t=0;t<4;++t){
        if (t>=ntap){ xoff[t][0]=0; xoff[t][1]=0; continue; }
        for (int ni=0;ni<2;++ni){
            int p = wx*32 + ni*16 + np;
            int r = p>>3, cc = p&7;
            xoff[t][ni] = ((r+1-dis[t])*9 + (cc+1-djs[t]))*32 + qq*8;
        }
    }

    floatx4 acc[2][2] = {};
    int a_oc  = tid>>2;         // 0..63
    int a_ic8 = (tid&3)*8;
    const u16* xbase = xst + (size_t)b*1024*512;

    for (int kk=0; kk<16; ++kk){
        int k0 = kk*32;
        // stage A tiles (one per tap)
        for (int t=0;t<ntap;++t){
            const uint4* src = (const uint4*)(wpack + ((size_t)pls[t]*262144
                                + (size_t)(m0 + a_oc)*512 + k0 + a_ic8));
            *(uint4*)(&Asm[t*2048 + a_oc*32 + a_ic8]) = *src;
        }
        // stage X halo 9x9 (zero-fill OOB => all boundary/tap-validity handled)
        for (int idx=tid; idx<324; idx+=256){
            int pxi = idx>>2;
            int ic8 = (idx&3)*8;
            int ri = pxi/9, ci = pxi - ri*9;
            int gi = Y0 - 1 + ri, gj = X0 - 1 + ci;
            uint4 val;
            if (gi>=0 && gi<32 && gj>=0 && gj<32)
                val = *(const uint4*)(xbase + ((size_t)(gi*32+gj)*512 + k0 + ic8));
            else
                val = make_uint4(0,0,0,0);
            *(uint4*)(&Xsm[pxi*32 + ic8]) = val;
        }
        __syncthreads();
        for (int t=0;t<ntap;++t){
            short8 a0 = *(const short8*)(&Asm[t*2048 + aoff0]);
            short8 a1 = *(const short8*)(&Asm[t*2048 + aoff1]);
            short8 b0 = *(const short8*)(&Xsm[xoff[t][0]]);
            short8 b1 = *(const short8*)(&Xsm[xoff[t][1]]);
            acc[0][0] = __builtin_amdgcn_mfma_f32_16x16x32_bf16(a0,b0,acc[0][0],0,0,0);
            acc[0][1] = __builtin_amdgcn_mfma_f32_16x16x32_bf16(a0,b1,acc[0][1],0,0,0);
            acc[1][0] = __builtin_amdgcn_mfma_f32_16x16x32_bf16(a1,b0,acc[1][0],0,0,0);
            acc[1][1] = __builtin_amdgcn_mfma_f32_16x16x32_bf16(a1,b1,acc[1][1],0,0,0);
        }
        __syncthreads();
    }
    // epilogue: D layout col=lane&15 (pixel), row=(lane>>4)*4+reg (oc)
    for (int ni=0; ni<2; ++ni){
        int p = wx*32 + ni*16 + np;
        int r = p>>3, cc = p&7;
        int Yp = Y0 + r, Xp = X0 + cc;
        if (Yp < Hc && Xp < Wc){
            #pragma unroll
            for (int mi=0; mi<2; ++mi){
                #pragma unroll
                for (int reg=0; reg<4; ++reg){
                    int oc = m0 + wy*32 + mi*16 + qq*4 + reg;
                    tout[(size_t)(b*512+oc)*4225 + offc + Yp*Wc + Xp] =
                        f2bf(acc[mi][ni][reg]);
                }
            }
        }
    }
}

// ---- stage 2: 4x4 blur (zero-pad t 65x65) * dscale -> out fp32 ----
__global__ __launch_bounds__(256) void k_blur(const u16* __restrict__ t,
                                              const float* __restrict__ dscale,
                                              float* __restrict__ out){
    int b = blockIdx.z;
    int oc = blockIdx.y;
    int Y = blockIdx.x*4 + (threadIdx.x>>6);
    int X = threadIdx.x & 63;
    const float kf[4] = {1.f,3.f,3.f,1.f};
    const u16* tb = t + (size_t)(b*512+oc)*4225;
    float sum = 0.f;
    #pragma unroll
    for (int dy=0; dy<4; ++dy){
        int y = Y-1+dy;
        if (y<0 || y>64) continue;
        int pyy = y&1, Yp = y>>1;
        float rs = 0.f;
        #pragma unroll
        for (int dx=0; dx<4; ++dx){
            int x = X-1+dx;
            if (x<0 || x>64) continue;
            int pxx = x&1, Xp = x>>1;
            int cls = pyy*2+pxx;
            int off = (cls==0)?0:(cls==1)?1089:(cls==2)?2145:3201;
            int Wc = pxx?32:33;
            rs += kf[dx]*bf2f(tb[off + Yp*Wc + Xp]);
        }
        sum += kf[dy]*rs;
    }
    out[((size_t)(b*512+oc)*64 + Y)*64 + X] = dscale[b*512+oc]*sum*(1.f/16.f);
}

extern "C" void kernel_launch(void* const* d_in, const int* in_sizes, int n_in,
                              void* d_out, int out_size, void* d_ws, size_t ws_size,
                              hipStream_t stream){
    const float* input  = (const float*)d_in[0];
    const float* style  = (const float*)d_in[1];
    const float* weight = (const float*)d_in[2];
    const float* mw     = (const float*)d_in[3];
    const float* mb     = (const float*)d_in[4];
    float* out = (float*)d_out;
    char* ws = (char*)d_ws;
    float* s     = (float*)(ws + OFF_S);
    float* ds    = (float*)(ws + OFF_DS);
    float* wsum  = (float*)(ws + OFF_WSUM);
    u16*   wpack = (u16*)(ws + OFF_WPACK);
    u16*   xst   = (u16*)(ws + OFF_XST);
    u16*   t     = (u16*)(ws + OFF_T);

    k_style <<<2048, 256, 0, stream>>>(style, mw, mb, s);
    k_wsum  <<<1024, 256, 0, stream>>>(weight, wsum);
    k_dscale<<<2048, 256, 0, stream>>>(s, wsum, ds);
    k_wpack <<<1024, 256, 0, stream>>>(weight, wpack);
    k_xst   <<<512,  256, 0, stream>>>(input, s, xst);
    k_conv  <<<dim3(81,8,16), 256, 0, stream>>>(wpack, xst, t);
    k_blur  <<<dim3(16,512,16), 256, 0, stream>>>(t, ds, out);
}

// Round 2
// 357.079 us; speedup vs baseline: 2.1206x; 2.1206x over previous
//
#include <hip/hip_runtime.h>
#include <stdint.h>

typedef unsigned int uint32;
typedef unsigned short u16;
typedef short short8 __attribute__((ext_vector_type(8)));
typedef float floatx4 __attribute__((ext_vector_type(4)));

// ---------------- workspace layout (bytes) ----------------
#define OFF_S      0u           // s[16][512] f32        : 32768
#define OFF_DS     32768u       // dscale[16][512] f32   : 32768
#define OFF_WSUM   65536u       // wsum[512][512] f32    : 1 MB
#define OFF_WPACK  1114112u     // wpack[9][512][512] bf16 (m=tap*512+oc, k=ic): 4.5 MB
#define OFF_XST    5832704u     // xst[16*1024][512] bf16 (n=b*1024+px, k=ic): 16 MB
#define OFF_U      22609920u    // U[4608][NB*1024] bf16 : NB*9.44 MB

__device__ __forceinline__ u16 f2bf(float x){
    uint32 u = __float_as_uint(x);
    uint32 r = (u + 0x7FFFu + ((u>>16)&1u)) >> 16;
    return (u16)r;
}
__device__ __forceinline__ float bf2f(u16 h){
    return __uint_as_float(((uint32)h)<<16);
}

#define GLL16(gp, lp) \
    __builtin_amdgcn_global_load_lds( \
        (const __attribute__((address_space(1))) void*)(gp), \
        (__attribute__((address_space(3))) void*)(lp), 16, 0, 0)

// ---- s[b][ic] = style[b]·mod_weight[ic] * mod_scale + mod_bias[ic] ----
__global__ __launch_bounds__(256) void k_style(const float* __restrict__ style,
                                               const float* __restrict__ mw,
                                               const float* __restrict__ mb,
                                               float* __restrict__ s){
    int gid = blockIdx.x*4 + (threadIdx.x>>6);
    int lane = threadIdx.x & 63;
    int b = gid>>9, ic = gid & 511;
    const float* sp = style + b*512;
    const float* wp = mw + (size_t)ic*512;
    float acc = 0.f;
    for (int d=lane; d<512; d+=64) acc += sp[d]*wp[d];
    for (int off=32; off; off>>=1) acc += __shfl_down(acc, off, 64);
    if (lane==0) s[b*512+ic] = acc*0.044194173824159216f + mb[ic]; // 1/sqrt(512)
}

// ---- fused: wsum[oc][ic] = sum_k w^2 ; wpack[tap][oc][ic] = bf16(w) ----
__global__ __launch_bounds__(256) void k_wprep(const float* __restrict__ w,
                                               float* __restrict__ wsum,
                                               u16* __restrict__ wp){
    int idx = blockIdx.x*256 + threadIdx.x; // oc*512+ic, 262144
    const float* p = w + (size_t)idx*9;
    float vv[9]; float a = 0.f;
    #pragma unroll
    for (int t=0;t<9;++t){ float v=p[t]; vv[t]=v; a += v*v; }
    wsum[idx] = a;
    #pragma unroll
    for (int t=0;t<9;++t) wp[(size_t)t*262144 + idx] = f2bf(vv[t]);
}

// ---- dscale[b][oc] = conv_scale * rsqrt(conv_scale^2 * sum_ic s^2*wsum + eps) ----
__global__ __launch_bounds__(256) void k_dscale(const float* __restrict__ s,
                                                const float* __restrict__ wsum,
                                                float* __restrict__ ds){
    int gid = blockIdx.x*4 + (threadIdx.x>>6);
    int lane = threadIdx.x & 63;
    int b = gid>>9, oc = gid & 511;
    const float* sp = s + b*512;
    const float* wp = wsum + (size_t)oc*512;
    float acc=0.f;
    for (int d=lane; d<512; d+=64){ float sv = sp[d]; acc += sv*sv*wp[d]; }
    for (int off=32; off; off>>=1) acc += __shfl_down(acc, off, 64);
    if (lane==0){
        const float cs = 0.014731391274719738f; // 1/sqrt(512*9)
        ds[b*512+oc] = cs * rsqrtf(cs*cs*acc + 1e-8f);
    }
}

// ---- xst[b*1024+px][ic] = bf16(input[b][ic][px] * s[b][ic]) via LDS transpose ----
__global__ __launch_bounds__(256) void k_xst(const float* __restrict__ in,
                                             const float* __restrict__ s,
                                             u16* __restrict__ xst){
    int bx = blockIdx.x;          // b*32 + i
    int b = bx>>5, i = bx&31;
    __shared__ u16 tr[32*520];    // [j][ic], stride 520 keeps 16B align + bank spread
    int tid = threadIdx.x;
    int j = tid & 31;
    for (int ic = tid>>5; ic < 512; ic += 8){
        float v = in[((size_t)(b*512+ic)*32 + i)*32 + j] * s[b*512+ic];
        tr[j*520 + ic] = f2bf(v);
    }
    __syncthreads();
    for (int v = tid; v < 2048; v += 256){
        int jj = v>>6, ic8 = (v&63)*8;
        *(uint4*)(xst + (size_t)(b*1024 + i*32 + jj)*512 + ic8) =
            *(const uint4*)(&tr[jj*520 + ic8]);
    }
}

// ---- GEMM: U[m][n] = sum_k wpack[m][k] * xst[n][k], m<4608, n<Ncols ----
// 128x128 tile, BK=64, global_load_lds(16B), XOR-swizzled LDS.
__global__ __launch_bounds__(256) void k_gemm(const u16* __restrict__ A,
                                              const u16* __restrict__ Bx,
                                              u16* __restrict__ C,
                                              int Ncols){
    int n0 = blockIdx.x * 128;
    int m0 = blockIdx.y * 128;
    int tid = threadIdx.x, lane = tid & 63, w = tid >> 6;
    int wm = w>>1, wn = w&1;
    int np = lane & 15, qq = lane >> 4;

    __shared__ __align__(16) u16 Asm[128*64];
    __shared__ __align__(16) u16 Bsm[128*64];

    int rsub = lane >> 3;                 // 0..7 row-within-8
    int gsw  = (lane & 7) ^ rsub;        // swizzled k-group fetched by this lane

    floatx4 acc[4][4] = {};

    for (int k0 = 0; k0 < 512; k0 += 64){
        #pragma unroll
        for (int q = 0; q < 4; ++q){
            int row = q*32 + w*8 + rsub;
            GLL16(A + (size_t)(m0+row)*512 + k0 + gsw*8, &Asm[(q*32 + w*8)*64]);
        }
        #pragma unroll
        for (int q = 0; q < 4; ++q){
            int row = q*32 + w*8 + rsub;
            GLL16(Bx + (size_t)(n0+row)*512 + k0 + gsw*8, &Bsm[(q*32 + w*8)*64]);
        }
        __syncthreads();
        #pragma unroll
        for (int kk = 0; kk < 2; ++kk){
            short8 af[4], bf[4];
            #pragma unroll
            for (int mf = 0; mf < 4; ++mf){
                int row = wm*64 + mf*16 + np;
                int gs = (kk*4 + qq) ^ (np & 7);
                af[mf] = *(const short8*)(&Asm[row*64 + gs*8]);
            }
            #pragma unroll
            for (int nf = 0; nf < 4; ++nf){
                int row = wn*64 + nf*16 + np;
                int gs = (kk*4 + qq) ^ (np & 7);
                bf[nf] = *(const short8*)(&Bsm[row*64 + gs*8]);
            }
            #pragma unroll
            for (int mf = 0; mf < 4; ++mf)
                #pragma unroll
                for (int nf = 0; nf < 4; ++nf)
                    acc[mf][nf] = __builtin_amdgcn_mfma_f32_16x16x32_bf16(
                        af[mf], bf[nf], acc[mf][nf], 0,0,0);
        }
        __syncthreads();
    }
    // C/D: col(n)=lane&15, row(m)=(lane>>4)*4+reg
    #pragma unroll
    for (int mf = 0; mf < 4; ++mf){
        #pragma unroll
        for (int reg = 0; reg < 4; ++reg){
            int m = m0 + wm*64 + mf*16 + qq*4 + reg;
            size_t base = (size_t)m * Ncols;
            #pragma unroll
            for (int nf = 0; nf < 4; ++nf){
                int n = n0 + wn*64 + nf*16 + np;
                C[base + n] = f2bf(acc[mf][nf][reg]);
            }
        }
    }
}

// ---- blur: per (b,oc) plane: gather 9 taps -> t(65x65 fp32) -> separable 1,3,3,1 ----
__global__ __launch_bounds__(256) void k_blur2(const u16* __restrict__ U,
                                               const float* __restrict__ ds,
                                               float* __restrict__ out,
                                               int b0, int Ncols){
    int oc = blockIdx.x;
    int bp = blockIdx.y;
    int b  = b0 + bp;
    __shared__ __align__(16) char ubuf[18432];   // U taps (9*1024*2B), reused as hsm
    __shared__ __align__(16) float tsm[65*66];
    u16*  Usm = (u16*)ubuf;
    float* hsm = (float*)ubuf;
    int tid = threadIdx.x;

    const u16* src0 = U + (size_t)oc*Ncols + (size_t)bp*1024;
    size_t tapstride = (size_t)512 * Ncols;
    for (int i = tid; i < 1152; i += 256){
        int tap = i>>7, c8 = i & 127;
        *(uint4*)(&Usm[tap*1024 + c8*8]) = *(const uint4*)(src0 + tap*tapstride + c8*8);
    }
    __syncthreads();

    // t[y][x] = sum over taps (a,b) with y-a,x-b even: U[a*3+b][(y-a)/2][(x-b)/2]
    for (int idx = tid; idx < 4225; idx += 256){
        float v = 0.f;
        if (idx < 1089){                       // ee: 33x33, taps {0,2}x{0,2}
            int Y = idx/33, X = idx - Y*33;
            #pragma unroll
            for (int da = 0; da < 2; ++da){
                int iy = Y - da;
                if ((unsigned)iy < 32u){
                    #pragma unroll
                    for (int db = 0; db < 2; ++db){
                        int jx = X - db;
                        if ((unsigned)jx < 32u)
                            v += bf2f(Usm[(6*da + 2*db)*1024 + iy*32 + jx]);
                    }
                }
            }
            tsm[(2*Y)*66 + 2*X] = v;
        } else if (idx < 2145){                // eo: 33x32, taps a in {0,2}, b=1
            int loc = idx - 1089, Y = loc>>5, X = loc & 31;
            #pragma unroll
            for (int da = 0; da < 2; ++da){
                int iy = Y - da;
                if ((unsigned)iy < 32u)
                    v += bf2f(Usm[(6*da + 1)*1024 + iy*32 + X]);
            }
            tsm[(2*Y)*66 + 2*X + 1] = v;
        } else if (idx < 3201){                // oe: 32x33, a=1, b in {0,2}
            int loc = idx - 2145, Y = loc/33, X = loc - Y*33;
            #pragma unroll
            for (int db = 0; db < 2; ++db){
                int jx = X - db;
                if ((unsigned)jx < 32u)
                    v += bf2f(Usm[(3 + 2*db)*1024 + Y*32 + jx]);
            }
            tsm[(2*Y+1)*66 + 2*X] = v;
        } else {                               // oo: 32x32, tap (1,1)
            int loc = idx - 3201, Y = loc>>5, X = loc & 31;
            v = bf2f(Usm[4*1024 + Y*32 + X]);
            tsm[(2*Y+1)*66 + 2*X + 1] = v;
        }
    }
    __syncthreads();

    // horizontal pass: h[y][X] over y in [0,65), X in [0,64)
    for (int idx = tid; idx < 4160; idx += 256){
        int y = idx>>6, X = idx & 63;
        const float* trow = tsm + y*66;
        float v = 3.f*trow[X] + 3.f*trow[X+1];
        if (X > 0)  v += trow[X-1];
        if (X < 63) v += trow[X+2];
        hsm[y*64 + X] = v;
    }
    __syncthreads();

    // vertical pass + scale + store
    float dsc = ds[b*512 + oc] * (1.f/16.f);
    float* op = out + (size_t)(b*512 + oc) * 4096;
    for (int idx = tid; idx < 4096; idx += 256){
        int Y = idx>>6, X = idx & 63;
        float v = 3.f*hsm[Y*64 + X] + 3.f*hsm[(Y+1)*64 + X];
        if (Y > 0)  v += hsm[(Y-1)*64 + X];
        if (Y < 63) v += hsm[(Y+2)*64 + X];
        op[idx] = dsc * v;
    }
}

extern "C" void kernel_launch(void* const* d_in, const int* in_sizes, int n_in,
                              void* d_out, int out_size, void* d_ws, size_t ws_size,
                              hipStream_t stream){
    const float* input  = (const float*)d_in[0];
    const float* style  = (const float*)d_in[1];
    const float* weight = (const float*)d_in[2];
    const float* mw     = (const float*)d_in[3];
    const float* mb     = (const float*)d_in[4];
    float* out = (float*)d_out;
    char* ws = (char*)d_ws;
    float* s     = (float*)(ws + OFF_S);
    float* ds    = (float*)(ws + OFF_DS);
    float* wsum  = (float*)(ws + OFF_WSUM);
    u16*   wpack = (u16*)(ws + OFF_WPACK);
    u16*   xst   = (u16*)(ws + OFF_XST);
    u16*   U     = (u16*)(ws + OFF_U);

    // pick batches-per-pass by available workspace (constant across calls)
    int NB;
    if      (ws_size >= (size_t)OFF_U + (size_t)4608*16384*2) NB = 16;
    else if (ws_size >= (size_t)OFF_U + (size_t)4608*8192*2)  NB = 8;
    else                                                       NB = 4;
    int npass = 16 / NB;
    int Ncols = NB * 1024;

    k_style <<<2048, 256, 0, stream>>>(style, mw, mb, s);
    k_wprep <<<1024, 256, 0, stream>>>(weight, wsum, wpack);
    k_dscale<<<2048, 256, 0, stream>>>(s, wsum, ds);
    k_xst   <<<512,  256, 0, stream>>>(input, s, xst);

    for (int p = 0; p < npass; ++p){
        const u16* xp = xst + (size_t)p * NB * 1024 * 512;
        k_gemm <<<dim3(Ncols/128, 36), 256, 0, stream>>>(wpack, xp, U, Ncols);
        k_blur2<<<dim3(512, NB),       256, 0, stream>>>(U, ds, out, p*NB, Ncols);
    }
}

// Round 3
// 338.268 us; speedup vs baseline: 2.2385x; 1.0556x over previous
//
#include <hip/hip_runtime.h>
#include <stdint.h>

typedef unsigned int uint32;
typedef unsigned short u16;
typedef short short8 __attribute__((ext_vector_type(8)));
typedef float floatx4 __attribute__((ext_vector_type(4)));

// ---------------- workspace layout (bytes) ----------------
#define OFF_S      0u           // s[16][512] f32        : 32768
#define OFF_DS     32768u       // dscale[16][512] f32   : 32768
#define OFF_WSUM   65536u       // wsum[512][512] f32    : 1 MB
#define OFF_WPACK  1114112u     // wpack[9][512][512] bf16 (m=tap*512+oc, k=ic): 4.5 MB
#define OFF_XST    5832704u     // xst[16*1024][512] bf16 (n=b*1024+px, k=ic): 16 MB
#define OFF_U      22609920u    // U[4608][NB*1024] bf16 : NB*9.44 MB

__device__ __forceinline__ u16 f2bf(float x){
    uint32 u = __float_as_uint(x);
    uint32 r = (u + 0x7FFFu + ((u>>16)&1u)) >> 16;
    return (u16)r;
}
__device__ __forceinline__ float bf2f(u16 h){
    return __uint_as_float(((uint32)h)<<16);
}

#define GLL16(gp, lp) \
    __builtin_amdgcn_global_load_lds( \
        (const __attribute__((address_space(1))) void*)(gp), \
        (__attribute__((address_space(3))) void*)(lp), 16, 0, 0)

// ---- s[b][ic] = style[b]·mod_weight[ic] * mod_scale + mod_bias[ic] ----
__global__ __launch_bounds__(256) void k_style(const float* __restrict__ style,
                                               const float* __restrict__ mw,
                                               const float* __restrict__ mb,
                                               float* __restrict__ s){
    int gid = blockIdx.x*4 + (threadIdx.x>>6);
    int lane = threadIdx.x & 63;
    int b = gid>>9, ic = gid & 511;
    const float* sp = style + b*512;
    const float* wp = mw + (size_t)ic*512;
    float acc = 0.f;
    for (int d=lane; d<512; d+=64) acc += sp[d]*wp[d];
    for (int off=32; off; off>>=1) acc += __shfl_down(acc, off, 64);
    if (lane==0) s[b*512+ic] = acc*0.044194173824159216f + mb[ic]; // 1/sqrt(512)
}

// ---- fused: wsum[oc][ic] = sum_k w^2 ; wpack[tap][oc][ic] = bf16(w) ----
__global__ __launch_bounds__(256) void k_wprep(const float* __restrict__ w,
                                               float* __restrict__ wsum,
                                               u16* __restrict__ wp){
    int idx = blockIdx.x*256 + threadIdx.x; // oc*512+ic, 262144
    const float* p = w + (size_t)idx*9;
    float vv[9]; float a = 0.f;
    #pragma unroll
    for (int t=0;t<9;++t){ float v=p[t]; vv[t]=v; a += v*v; }
    wsum[idx] = a;
    #pragma unroll
    for (int t=0;t<9;++t) wp[(size_t)t*262144 + idx] = f2bf(vv[t]);
}

// ---- dscale[b][oc] = conv_scale * rsqrt(conv_scale^2 * sum_ic s^2*wsum + eps) ----
__global__ __launch_bounds__(256) void k_dscale(const float* __restrict__ s,
                                                const float* __restrict__ wsum,
                                                float* __restrict__ ds){
    int gid = blockIdx.x*4 + (threadIdx.x>>6);
    int lane = threadIdx.x & 63;
    int b = gid>>9, oc = gid & 511;
    const float* sp = s + b*512;
    const float* wp = wsum + (size_t)oc*512;
    float acc=0.f;
    for (int d=lane; d<512; d+=64){ float sv = sp[d]; acc += sv*sv*wp[d]; }
    for (int off=32; off; off>>=1) acc += __shfl_down(acc, off, 64);
    if (lane==0){
        const float cs = 0.014731391274719738f; // 1/sqrt(512*9)
        ds[b*512+oc] = cs * rsqrtf(cs*cs*acc + 1e-8f);
    }
}

// ---- xst[b*1024+px][ic] = bf16(input[b][ic][px] * s[b][ic]) via LDS transpose ----
__global__ __launch_bounds__(256) void k_xst(const float* __restrict__ in,
                                             const float* __restrict__ s,
                                             u16* __restrict__ xst){
    int bx = blockIdx.x;          // b*32 + i
    int b = bx>>5, i = bx&31;
    __shared__ u16 tr[32*520];
    int tid = threadIdx.x;
    int j = tid & 31;
    for (int ic = tid>>5; ic < 512; ic += 8){
        float v = in[((size_t)(b*512+ic)*32 + i)*32 + j] * s[b*512+ic];
        tr[j*520 + ic] = f2bf(v);
    }
    __syncthreads();
    for (int v = tid; v < 2048; v += 256){
        int jj = v>>6, ic8 = (v&63)*8;
        *(uint4*)(xst + (size_t)(b*1024 + i*32 + jj)*512 + ic8) =
            *(const uint4*)(&tr[jj*520 + ic8]);
    }
}

// ---- GEMM: U[m][n] = sum_k wpack[m][k] * xst[n][k], m<4608 ----
// 128x128 tile, BK=64, global_load_lds(16B), XOR-swizzled LDS,
// epilogue via LDS transpose -> dwordx4 coalesced stores.
__global__ __launch_bounds__(256) void k_gemm(const u16* __restrict__ A,
                                              const u16* __restrict__ Bx,
                                              u16* __restrict__ C,
                                              int Ncols){
    int n0 = blockIdx.x * 128;
    int m0 = blockIdx.y * 128;
    int tid = threadIdx.x, lane = tid & 63, w = tid >> 6;
    int wm = w>>1, wn = w&1;
    int np = lane & 15, qq = lane >> 4;

    __shared__ __align__(16) char smem[32768];
    u16* Asm = (u16*)smem;
    u16* Bsm = (u16*)(smem + 16384);
    u16* Csm = (u16*)smem;           // epilogue alias

    int rsub = lane >> 3;
    int gsw  = (lane & 7) ^ rsub;

    floatx4 acc[4][4] = {};

    for (int k0 = 0; k0 < 512; k0 += 64){
        #pragma unroll
        for (int q = 0; q < 4; ++q){
            int row = q*32 + w*8 + rsub;
            GLL16(A + (size_t)(m0+row)*512 + k0 + gsw*8, &Asm[(q*32 + w*8)*64]);
        }
        #pragma unroll
        for (int q = 0; q < 4; ++q){
            int row = q*32 + w*8 + rsub;
            GLL16(Bx + (size_t)(n0+row)*512 + k0 + gsw*8, &Bsm[(q*32 + w*8)*64]);
        }
        __syncthreads();
        #pragma unroll
        for (int kk = 0; kk < 2; ++kk){
            short8 af[4], bfr[4];
            #pragma unroll
            for (int mf = 0; mf < 4; ++mf){
                int row = wm*64 + mf*16 + np;
                int gs = (kk*4 + qq) ^ (np & 7);
                af[mf] = *(const short8*)(&Asm[row*64 + gs*8]);
            }
            #pragma unroll
            for (int nf = 0; nf < 4; ++nf){
                int row = wn*64 + nf*16 + np;
                int gs = (kk*4 + qq) ^ (np & 7);
                bfr[nf] = *(const short8*)(&Bsm[row*64 + gs*8]);
            }
            #pragma unroll
            for (int mf = 0; mf < 4; ++mf)
                #pragma unroll
                for (int nf = 0; nf < 4; ++nf)
                    acc[mf][nf] = __builtin_amdgcn_mfma_f32_16x16x32_bf16(
                        af[mf], bfr[nf], acc[mf][nf], 0,0,0);
        }
        __syncthreads();
    }
    // ---- epilogue: acc (MFMA layout) -> LDS (swizzled) -> coalesced stores ----
    #pragma unroll
    for (int mf = 0; mf < 4; ++mf){
        #pragma unroll
        for (int reg = 0; reg < 4; ++reg){
            int row = wm*64 + mf*16 + qq*4 + reg;
            #pragma unroll
            for (int nf = 0; nf < 4; ++nf){
                int col = wn*64 + nf*16 + np;
                int c = col >> 3;
                Csm[row*128 + ((c ^ (row & 15)) << 3) + (col & 7)] =
                    f2bf(acc[mf][nf][reg]);
            }
        }
    }
    __syncthreads();
    {
        int c = tid & 15;
        #pragma unroll
        for (int it = 0; it < 8; ++it){
            int row = it*16 + (tid >> 4);
            uint4 v = *(const uint4*)(&Csm[row*128 + ((c ^ (row & 15)) << 3)]);
            *(uint4*)(C + (size_t)(m0+row)*Ncols + n0 + c*8) = v;
        }
    }
}

// ---- blur v3: per (b,oc): U taps -> polyphase horizontal rows HR (bf16) -> vertical+out ----
// HR[a][i][X] = horizontal 1,3,3,1 of the virtual upsampled t-row sourced from rows (a,i).
__global__ __launch_bounds__(256) void k_blur2(const u16* __restrict__ U,
                                               const float* __restrict__ ds,
                                               float* __restrict__ out,
                                               int b0, int Ncols){
    int oc = blockIdx.x;
    int bp = blockIdx.y;
    int b  = b0 + bp;
    __shared__ __align__(16) u16 Usm[9*1024];    // 18 KB
    __shared__ __align__(16) u16 HRsm[3*32*64];  // 12 KB
    int tid = threadIdx.x;

    const u16* src0 = U + (size_t)oc*Ncols + (size_t)bp*1024;
    size_t tapstride = (size_t)512 * Ncols;
    #pragma unroll
    for (int it = 0; it < 5; ++it){
        int i = tid + it*256;
        if (i < 1152){
            int tap = i>>7, c8 = i & 127;
            *(uint4*)(&Usm[tap*1024 + c8*8]) =
                *(const uint4*)(src0 + tap*tapstride + c8*8);
        }
    }
    __syncthreads();

    // phase 2: HR rows. task = a*1024 + i*32 + u ; computes X=2u, 2u+1
    #pragma unroll
    for (int it = 0; it < 12; ++it){
        int task = tid + it*256;
        int a = task >> 10, rem = task & 1023;
        int i = rem >> 5, u = rem & 31;
        const u16* base = Usm + a*3072 + i*32;
        float u0  = bf2f(base[u]);
        float u1  = bf2f(base[1024 + u]);
        float u2  = bf2f(base[2048 + u]);
        float u0p = (u < 31) ? bf2f(base[u + 1])        : 0.f;
        float u1m = (u > 0)  ? bf2f(base[1024 + u - 1]) : 0.f;
        float u1p = (u < 31) ? bf2f(base[1024 + u + 1]) : 0.f;
        float u2m = (u > 0)  ? bf2f(base[2048 + u - 1]) : 0.f;
        float HRe = u1m + 3.f*(u0 + u2m + u1) + u0p + u2;
        float HRo = u0 + u2m + 3.f*(u1 + u0p + u2) + u1p;
        uint32 packed = (uint32)f2bf(HRe) | ((uint32)f2bf(HRo) << 16);
        *(uint32*)(&HRsm[(a*32 + i)*64 + 2*u]) = packed;
    }
    __syncthreads();

    // phase 3: vertical 1,3,3,1 over HR rows; float4 out
    float dsc = ds[b*512 + oc] * (1.f/16.f);
    float* op = out + (size_t)(b*512 + oc) * 4096;
    #pragma unroll
    for (int it = 0; it < 4; ++it){
        int task = tid + it*256;      // 1024 tasks: Y (64) x Xq (16)
        int Y = task >> 4, X0 = (task & 15) * 4;
        float o0=0.f,o1=0.f,o2=0.f,o3=0.f;
        int v = Y >> 1;
        #define ACCROW(aa, ii, ww) do{ \
            int _i = (ii); \
            if ((unsigned)_i < 32u){ \
                uint2 rv = *(const uint2*)(&HRsm[((aa)*32 + _i)*64 + X0]); \
                o0 += (ww)*__uint_as_float((rv.x & 0xffffu) << 16); \
                o1 += (ww)*__uint_as_float(rv.x & 0xffff0000u); \
                o2 += (ww)*__uint_as_float((rv.y & 0xffffu) << 16); \
                o3 += (ww)*__uint_as_float(rv.y & 0xffff0000u); \
            } }while(0)
        if ((Y & 1) == 0){
            ACCROW(1, v-1, 1.f);
            ACCROW(0, v,   3.f);
            ACCROW(2, v-1, 3.f);
            ACCROW(1, v,   3.f);
            ACCROW(0, v+1, 1.f);
            ACCROW(2, v,   1.f);
        } else {
            ACCROW(0, v,   1.f);
            ACCROW(2, v-1, 1.f);
            ACCROW(1, v,   3.f);
            ACCROW(0, v+1, 3.f);
            ACCROW(2, v,   3.f);
            ACCROW(1, v+1, 1.f);
        }
        #undef ACCROW
        float4 res = make_float4(dsc*o0, dsc*o1, dsc*o2, dsc*o3);
        *(float4*)(op + Y*64 + X0) = res;
    }
}

extern "C" void kernel_launch(void* const* d_in, const int* in_sizes, int n_in,
                              void* d_out, int out_size, void* d_ws, size_t ws_size,
                              hipStream_t stream){
    const float* input  = (const float*)d_in[0];
    const float* style  = (const float*)d_in[1];
    const float* weight = (const float*)d_in[2];
    const float* mw     = (const float*)d_in[3];
    const float* mb     = (const float*)d_in[4];
    float* out = (float*)d_out;
    char* ws = (char*)d_ws;
    float* s     = (float*)(ws + OFF_S);
    float* ds    = (float*)(ws + OFF_DS);
    float* wsum  = (float*)(ws + OFF_WSUM);
    u16*   wpack = (u16*)(ws + OFF_WPACK);
    u16*   xst   = (u16*)(ws + OFF_XST);
    u16*   U     = (u16*)(ws + OFF_U);

    int NB;
    if      (ws_size >= (size_t)OFF_U + (size_t)4608*16384*2) NB = 16;
    else if (ws_size >= (size_t)OFF_U + (size_t)4608*8192*2)  NB = 8;
    else                                                       NB = 4;
    int npass = 16 / NB;
    int Ncols = NB * 1024;

    k_style <<<2048, 256, 0, stream>>>(style, mw, mb, s);
    k_wprep <<<1024, 256, 0, stream>>>(weight, wsum, wpack);
    k_dscale<<<2048, 256, 0, stream>>>(s, wsum, ds);
    k_xst   <<<512,  256, 0, stream>>>(input, s, xst);

    for (int p = 0; p < npass; ++p){
        const u16* xp = xst + (size_t)p * NB * 1024 * 512;
        k_gemm <<<dim3(Ncols/128, 36), 256, 0, stream>>>(wpack, xp, U, Ncols);
        k_blur2<<<dim3(512, NB),       256, 0, stream>>>(U, ds, out, p*NB, Ncols);
    }
}